// Round 1
// baseline (1750.115 us; speedup 1.0000x reference)
//
#include <hip/hip_runtime.h>
#include <hip/hip_bf16.h>
#include <math.h>

#define N_FEAT 32
#define N_HID  64   // 2*N_FEAT
#define N_LAT  64
#define R_HID  128  // 2*N_LAT
#define TPT    8    // tracks per thread (contiguous -> exploits sorted ids)

// ---------------------------------------------------------------------------
// Kernel 1: fused phi MLP + segment-sum pooling.
// Each thread processes TPT contiguous tracks, accumulating the phi output in
// registers while the event id is unchanged; flushes via atomicAdd on change.
// Weights are read with wave-uniform indices -> scalar loads (SGPR operand to
// v_fma), so there is zero LDS pressure.
// ---------------------------------------------------------------------------
__global__ __launch_bounds__(256) void phi_pool_kernel(
    const float* __restrict__ x,
    const int*   __restrict__ eids,
    const float* __restrict__ w1, const float* __restrict__ b1,
    const float* __restrict__ w2, const float* __restrict__ b2,
    float* __restrict__ pooled, int n_tracks)
{
    long long start = (long long)(blockIdx.x * blockDim.x + threadIdx.x) * TPT;
    if (start >= n_tracks) return;

    float acc[N_LAT];
    int cur = -1;

    #pragma unroll 1
    for (int t = 0; t < TPT; ++t) {
        long long tr = start + t;
        if (tr >= n_tracks) break;
        int e = eids[tr];
        if (e != cur) {
            if (cur >= 0) {
                float* dst = pooled + (size_t)cur * N_LAT;
                #pragma unroll
                for (int m = 0; m < N_LAT; ++m) atomicAdd(dst + m, acc[m]);
            }
            cur = e;
            #pragma unroll
            for (int m = 0; m < N_LAT; ++m) acc[m] = 0.f;
        }

        // ---- layer 1: h1 = relu(x @ W1 + b1), x row is 32 floats ----
        float h1[N_HID];
        #pragma unroll
        for (int j = 0; j < N_HID; ++j) h1[j] = b1[j];

        const float4* xp = reinterpret_cast<const float4*>(x + (size_t)tr * N_FEAT);
        #pragma unroll 1
        for (int k4 = 0; k4 < N_FEAT / 4; ++k4) {
            float4 v = xp[k4];
            float xs[4] = {v.x, v.y, v.z, v.w};
            #pragma unroll
            for (int kk = 0; kk < 4; ++kk) {
                float xv = xs[kk];
                const float* wrow = w1 + (size_t)(k4 * 4 + kk) * N_HID;
                #pragma unroll
                for (int j = 0; j < N_HID; ++j) h1[j] += xv * wrow[j];
            }
        }
        #pragma unroll
        for (int j = 0; j < N_HID; ++j) h1[j] = fmaxf(h1[j], 0.f);

        // ---- layer 2: acc += relu(h1 @ W2 + b2), grouped by 16 outputs ----
        #pragma unroll
        for (int mg = 0; mg < N_LAT; mg += 16) {
            float h2[16];
            #pragma unroll
            for (int mm = 0; mm < 16; ++mm) h2[mm] = b2[mg + mm];
            #pragma unroll
            for (int j = 0; j < N_HID; ++j) {
                float hj = h1[j];
                const float* wrow = w2 + (size_t)j * N_LAT + mg;
                #pragma unroll
                for (int mm = 0; mm < 16; ++mm) h2[mm] += hj * wrow[mm];
            }
            #pragma unroll
            for (int mm = 0; mm < 16; ++mm) acc[mg + mm] += fmaxf(h2[mm], 0.f);
        }
    }

    if (cur >= 0) {
        float* dst = pooled + (size_t)cur * N_LAT;
        #pragma unroll
        for (int m = 0; m < N_LAT; ++m) atomicAdd(dst + m, acc[m]);
    }
}

// ---------------------------------------------------------------------------
// Kernel 2: rho MLP per event + sigmoid. One thread per event.
// ---------------------------------------------------------------------------
__global__ __launch_bounds__(256) void rho_kernel(
    const float* __restrict__ pooled,
    const float* __restrict__ w1, const float* __restrict__ b1,
    const float* __restrict__ w2, const float* __restrict__ b2,
    const float* __restrict__ w3, const float* __restrict__ b3,
    float* __restrict__ out, int n_events)
{
    int e = blockIdx.x * blockDim.x + threadIdx.x;
    if (e >= n_events) return;

    // ---- layer 1: r1 = relu(pooled @ W1 + b1)  [64 -> 128] ----
    float r1[R_HID];
    #pragma unroll
    for (int j = 0; j < R_HID; ++j) r1[j] = b1[j];

    const float4* pp = reinterpret_cast<const float4*>(pooled + (size_t)e * N_LAT);
    #pragma unroll 1
    for (int k4 = 0; k4 < N_LAT / 4; ++k4) {
        float4 v = pp[k4];
        float xs[4] = {v.x, v.y, v.z, v.w};
        #pragma unroll
        for (int kk = 0; kk < 4; ++kk) {
            float xv = xs[kk];
            const float* wrow = w1 + (size_t)(k4 * 4 + kk) * R_HID;
            #pragma unroll
            for (int j = 0; j < R_HID; ++j) r1[j] += xv * wrow[j];
        }
    }
    #pragma unroll
    for (int j = 0; j < R_HID; ++j) r1[j] = fmaxf(r1[j], 0.f);

    // ---- layer 2+3 fused: z = b3 + sum_m relu(r1 @ W2 + b2)[m] * w3[m] ----
    float z = b3[0];
    #pragma unroll
    for (int mg = 0; mg < N_LAT; mg += 16) {
        float r2[16];
        #pragma unroll
        for (int mm = 0; mm < 16; ++mm) r2[mm] = b2[mg + mm];
        #pragma unroll
        for (int j = 0; j < R_HID; ++j) {
            float rj = r1[j];
            const float* wrow = w2 + (size_t)j * N_LAT + mg;
            #pragma unroll
            for (int mm = 0; mm < 16; ++mm) r2[mm] += rj * wrow[mm];
        }
        #pragma unroll
        for (int mm = 0; mm < 16; ++mm) z += fmaxf(r2[mm], 0.f) * w3[mg + mm];
    }

    out[e] = 1.f / (1.f + expf(-z));
}

extern "C" void kernel_launch(void* const* d_in, const int* in_sizes, int n_in,
                              void* d_out, int out_size, void* d_ws, size_t ws_size,
                              hipStream_t stream) {
    const float* x      = (const float*)d_in[0];
    const int*   eids   = (const int*)  d_in[1];
    const float* phi_w1 = (const float*)d_in[2];
    const float* phi_b1 = (const float*)d_in[3];
    const float* phi_w2 = (const float*)d_in[4];
    const float* phi_b2 = (const float*)d_in[5];
    const float* rho_w1 = (const float*)d_in[6];
    const float* rho_b1 = (const float*)d_in[7];
    const float* rho_w2 = (const float*)d_in[8];
    const float* rho_b2 = (const float*)d_in[9];
    const float* rho_w3 = (const float*)d_in[10];
    const float* rho_b3 = (const float*)d_in[11];
    float* out = (float*)d_out;

    int n_tracks = in_sizes[1];
    int n_events = out_size;

    float* pooled = (float*)d_ws;  // [n_events, 64] accumulator
    hipMemsetAsync(pooled, 0, (size_t)n_events * N_LAT * sizeof(float), stream);

    int n_threads = (n_tracks + TPT - 1) / TPT;
    int n_blocks  = (n_threads + 255) / 256;
    phi_pool_kernel<<<n_blocks, 256, 0, stream>>>(
        x, eids, phi_w1, phi_b1, phi_w2, phi_b2, pooled, n_tracks);

    int r_blocks = (n_events + 255) / 256;
    rho_kernel<<<r_blocks, 256, 0, stream>>>(
        pooled, rho_w1, rho_b1, rho_w2, rho_b2, rho_w3, rho_b3, out, n_events);
}